// Round 19
// baseline (1189.232 us; speedup 1.0000x reference)
//
#include <hip/hip_runtime.h>
#include <hip/hip_fp16.h>
#include <cstdint>
#include <cstddef>

// OwnVanillaRNN R19: R18 (MFMA persistent, 960 us) + max register residency.
// R18 accounting: MFMA floor 2483 cyc/step (49% util ✓); co-cost = LDS
// weight streaming (16 full-wave b128/wave/step ~ 1540 cyc) + tail. LDS
// stream cost is proportional to LDS-resident weight bytes -> shift 4 more
// frags to registers: NREG 48->52 (208 frag-regs; ~32 frags sit in AGPRs
// which MFMA consumes DIRECTLY -- the one instr class with that privilege),
// NLDS 16->12 (96 KB). Tripwire: WRITE_SIZE MB-scale => NREG overflow.

constexpr int BATCH = 256;
constexpr int SEQ   = 512;
constexpr int IN    = 64;
constexpr int HID   = 512;
constexpr int OUT   = 64;
constexpr int TW    = 512;        // 8 waves
constexpr int FRW   = 64;         // frags/wave = 4 m-tiles x 16 k-tiles
constexpr int NREG  = 52;         // f = 0..51 named-SSA (m-tiles 0-2 + kt0-3 of 3)
constexpr int NLDS  = 12;         // f = 52..63 in LDS (m-tile 3, kt 4..15)

typedef _Float16 f16x8 __attribute__((ext_vector_type(8)));
typedef _Float16 half2v __attribute__((ext_vector_type(2)));
typedef float    f32x4 __attribute__((ext_vector_type(4)));

__device__ __forceinline__ uint32_t packh2(float lo, float hi) {
    return (uint32_t)__half_as_ushort(__float2half(lo)) |
           ((uint32_t)__half_as_ushort(__float2half(hi)) << 16);
}
__device__ __forceinline__ float h2f(uint32_t bits16) {
    return __half2float(__builtin_bit_cast(__half, (unsigned short)(bits16 & 0xFFFFu)));
}
__device__ __forceinline__ float fdot2(uint32_t w, uint32_t h, float acc) {
    return __builtin_amdgcn_fdot2(__builtin_bit_cast(half2v, w),
                                  __builtin_bit_cast(half2v, h), acc, false);
}

// Wpk[(w*64 + f)*64 + l]: wave w, frag f = i*16 + kt. A-layout (HW-verified):
// lane l holds Wh[64w + 16i + (l&15)][32kt + 8*(l>>4) + j], j = 0..7.
__global__ __launch_bounds__(256, 1)
void prep_w(const float* __restrict__ Wh, uint4* __restrict__ Wpk) {
    const int idx = blockIdx.x * 256 + threadIdx.x;   // 8*64*64 = 32768
    const int l  = idx & 63;
    const int wf = idx >> 6;
    const int w  = wf >> 6, f = wf & 63;
    const int i  = f >> 4, kt = f & 15;
    const int o  = 64 * w + 16 * i + (l & 15);
    const int d0 = 32 * kt + 8 * (l >> 4);
    const float* src = Wh + (size_t)o * HID + d0;
    uint4 d;
    d.x = packh2(src[0], src[1]);
    d.y = packh2(src[2], src[3]);
    d.z = packh2(src[4], src[5]);
    d.w = packh2(src[6], src[7]);
    Wpk[idx] = d;
}

// XP[b][t][c] = x[b][t][:] @ Wx[c][:] + bx[c] + bh[c], f16 (R13-proven).
__global__ __launch_bounds__(256, 1)
void prep_xp(const float* __restrict__ x, const float* __restrict__ Wx,
             const float* __restrict__ bx, const float* __restrict__ bh,
             __half* __restrict__ XPh) {
    __shared__ uint32_t xs2[16][32];
    const int tid = threadIdx.x;
    const size_t R0 = (size_t)blockIdx.x * 16;

    for (int e = tid; e < 16 * 32; e += 256) {
        const int r = e >> 5, j = e & 31;
        const float2 v = *(const float2*)(x + (R0 + r) * IN + 2 * j);
        xs2[r][j] = packh2(v.x, v.y);
    }
    const int c0 = 2 * tid, c1 = c0 + 1;
    uint32_t wa[32], wb[32];
    #pragma unroll
    for (int q = 0; q < 16; ++q) {
        const float4 va = *(const float4*)(Wx + (size_t)c0 * IN + 4 * q);
        wa[2 * q] = packh2(va.x, va.y); wa[2 * q + 1] = packh2(va.z, va.w);
        const float4 vb = *(const float4*)(Wx + (size_t)c1 * IN + 4 * q);
        wb[2 * q] = packh2(vb.x, vb.y); wb[2 * q + 1] = packh2(vb.z, vb.w);
    }
    const float b0 = bx[c0] + bh[c0], b1 = bx[c1] + bh[c1];
    __syncthreads();

    for (int r = 0; r < 16; ++r) {
        float a0 = b0, a1 = b1;
        #pragma unroll
        for (int j = 0; j < 32; ++j) {
            const uint32_t hx = xs2[r][j];
            a0 = fdot2(wa[j], hx, a0);
            a1 = fdot2(wb[j], hx, a1);
        }
        ((uint32_t*)XPh)[((R0 + r) * HID + c0) >> 1] = packh2(a0, a1);
    }
}

#define FR_LIST(M) \
  M(0)  M(1)  M(2)  M(3)  M(4)  M(5)  M(6)  M(7)  M(8)  M(9)  M(10) M(11) \
  M(12) M(13) M(14) M(15) M(16) M(17) M(18) M(19) M(20) M(21) M(22) M(23) \
  M(24) M(25) M(26) M(27) M(28) M(29) M(30) M(31) M(32) M(33) M(34) M(35) \
  M(36) M(37) M(38) M(39) M(40) M(41) M(42) M(43) M(44) M(45) M(46) M(47) \
  M(48) M(49) M(50) M(51)

__global__ __launch_bounds__(TW, 2)
__attribute__((amdgpu_waves_per_eu(2, 2)))
void rnn_main(const __half* __restrict__ XPh, const float* __restrict__ Wy,
              const float* __restrict__ by, const uint4* __restrict__ Wpk,
              float* __restrict__ y) {
    __shared__ uint4 wl[NLDS * TW];                 // 96 KB: m-tile-3 kt4..15
    __shared__ __align__(16) __half hb2[2][HID];    // double-buffered h
    __shared__ __align__(16) __half zsrc[8];        // 16B zeros (B cols 1-15)

    const int b = blockIdx.x, t = threadIdx.x;
    const int w = t >> 6, l = t & 63, g = l >> 4;
    const bool real = (l & 15) == 0;

    // ---- one-time: stage LDS frags (coalesced) ----
    #pragma unroll
    for (int j = 0; j < NLDS; ++j)
        wl[j * TW + t] = Wpk[((size_t)w * FRW + NREG + j) * 64 + l];

    // ---- one-time: 52 A-frags as named SSA (208 regs, arch+AGPR;
    // MFMA reads AGPRs directly -> no reload tax) ----
    const uint4* wp = Wpk + (size_t)w * FRW * 64 + l;
#define DECL_W(f) const f16x8 w##f = __builtin_bit_cast(f16x8, wp[(f) * 64]);
    FR_LIST(DECL_W)
#undef DECL_W

    hb2[0][t] = __float2half(0.0f);   // h0 = 0 (t covers 512)
    if (t < 8) zsrc[t] = __float2half(0.0f);

    // XP base for this lane's 4 m-tile row groups (rows 64w+16i+4g..+3).
    const __half* XPb = XPh + (size_t)b * SEQ * HID + (64 * w + 4 * g);
    uint2 xq0, xq1, xq2, xq3;
    if (real) {
        xq0 = *(const uint2*)(XPb +  0);
        xq1 = *(const uint2*)(XPb + 16);
        xq2 = *(const uint2*)(XPb + 32);
        xq3 = *(const uint2*)(XPb + 48);
    }
    __syncthreads();

    const int bstep = real ? 4 : 0;

    #pragma unroll 1
    for (int tt = 0; tt < SEQ; ++tt) {
        const int c = tt & 1;
        uint2 nxq0, nxq1, nxq2, nxq3;
        if (real && tt + 1 < SEQ) {
            const __half* xn = XPb + (size_t)(tt + 1) * HID;
            nxq0 = *(const uint2*)(xn +  0);
            nxq1 = *(const uint2*)(xn + 16);
            nxq2 = *(const uint2*)(xn + 32);
            nxq3 = *(const uint2*)(xn + 48);
        }

        const uint4* bq = real ? ((const uint4*)&hb2[c][0]) + g
                               : (const uint4*)zsrc;
        f32x4 acc0 = {0.f,0.f,0.f,0.f}, acc1 = {0.f,0.f,0.f,0.f};
        f32x4 acc2 = {0.f,0.f,0.f,0.f}, acc3 = {0.f,0.f,0.f,0.f};

        // m-tile 3: kt 0..3 from registers (w48..w51), kt 4..15 from LDS.
#define KSR(kt, fa, fb, fc, fd) { \
        const f16x8 bfr = __builtin_bit_cast(f16x8, *bq); bq += bstep; \
        acc0 = __builtin_amdgcn_mfma_f32_16x16x32_f16(fa, bfr, acc0, 0, 0, 0); \
        acc1 = __builtin_amdgcn_mfma_f32_16x16x32_f16(fb, bfr, acc1, 0, 0, 0); \
        acc2 = __builtin_amdgcn_mfma_f32_16x16x32_f16(fc, bfr, acc2, 0, 0, 0); \
        acc3 = __builtin_amdgcn_mfma_f32_16x16x32_f16(fd, bfr, acc3, 0, 0, 0); }
#define KSL(kt, fa, fb, fc) { \
        const f16x8 bfr = __builtin_bit_cast(f16x8, *bq); bq += bstep; \
        const f16x8 wv  = __builtin_bit_cast(f16x8, wl[((kt) - 4) * TW + t]); \
        acc0 = __builtin_amdgcn_mfma_f32_16x16x32_f16(fa, bfr, acc0, 0, 0, 0); \
        acc1 = __builtin_amdgcn_mfma_f32_16x16x32_f16(fb, bfr, acc1, 0, 0, 0); \
        acc2 = __builtin_amdgcn_mfma_f32_16x16x32_f16(fc, bfr, acc2, 0, 0, 0); \
        acc3 = __builtin_amdgcn_mfma_f32_16x16x32_f16(wv, bfr, acc3, 0, 0, 0); }
        KSR(0,  w0,  w16, w32, w48)  KSR(1,  w1,  w17, w33, w49)
        KSR(2,  w2,  w18, w34, w50)  KSR(3,  w3,  w19, w35, w51)
        KSL(4,  w4,  w20, w36)       KSL(5,  w5,  w21, w37)
        KSL(6,  w6,  w22, w38)       KSL(7,  w7,  w23, w39)
        KSL(8,  w8,  w24, w40)       KSL(9,  w9,  w25, w41)
        KSL(10, w10, w26, w42)       KSL(11, w11, w27, w43)
        KSL(12, w12, w28, w44)       KSL(13, w13, w29, w45)
        KSL(14, w14, w30, w46)       KSL(15, w15, w31, w47)
#undef KSR
#undef KSL

        // tanh + h-write: real lane 16g holds rows 64w+16i+4g..+3 (col 0).
        if (real) {
#define DOI(i, XQ) { \
            const float z0 = acc##i[0] + h2f(XQ.x); \
            const float z1 = acc##i[1] + h2f(XQ.x >> 16); \
            const float z2 = acc##i[2] + h2f(XQ.y); \
            const float z3 = acc##i[3] + h2f(XQ.y >> 16); \
            const float t0 = 1.f - 2.f * __builtin_amdgcn_rcpf(__expf(2.f * z0) + 1.f); \
            const float t1 = 1.f - 2.f * __builtin_amdgcn_rcpf(__expf(2.f * z1) + 1.f); \
            const float t2 = 1.f - 2.f * __builtin_amdgcn_rcpf(__expf(2.f * z2) + 1.f); \
            const float t3 = 1.f - 2.f * __builtin_amdgcn_rcpf(__expf(2.f * z3) + 1.f); \
            uint2 hw; hw.x = packh2(t0, t1); hw.y = packh2(t2, t3); \
            *(uint2*)&hb2[c ^ 1][64 * w + 16 * (i) + 4 * g] = hw; }
            DOI(0, xq0) DOI(1, xq1) DOI(2, xq2) DOI(3, xq3)
#undef DOI
            xq0 = nxq0; xq1 = nxq1; xq2 = nxq2; xq3 = nxq3;
        }
        __syncthreads();
    }

    // ---- epilogue: y = h_T @ Wy^T + by (final h in hb2[0]) ----
    if (t < OUT) {
        float acc = by[t];
        const float* wy = Wy + (size_t)t * HID;
        #pragma unroll 8
        for (int j = 0; j < HID; ++j)
            acc = fmaf(wy[j], __half2float(hb2[0][j]), acc);
        y[(size_t)b * OUT + t] = acc;
    }
}

extern "C" void kernel_launch(void* const* d_in, const int* in_sizes, int n_in,
                              void* d_out, int out_size, void* d_ws, size_t ws_size,
                              hipStream_t stream) {
    const float* x  = (const float*)d_in[0];
    const float* Wx = (const float*)d_in[1];
    const float* bx = (const float*)d_in[2];
    const float* Wh = (const float*)d_in[3];
    const float* bh = (const float*)d_in[4];
    const float* Wy = (const float*)d_in[5];
    const float* by = (const float*)d_in[6];
    float* y = (float*)d_out;

    uint4*  Wpk = (uint4*)d_ws;                          // 512 KB A-frags
    __half* XPh = (__half*)((char*)d_ws + (size_t)8 * FRW * 64 * 16);  // 128 MiB

    hipLaunchKernelGGL(prep_w, dim3(8 * FRW * 64 / 256), dim3(256), 0, stream,
                       Wh, Wpk);
    hipLaunchKernelGGL(prep_xp, dim3(BATCH * SEQ / 16), dim3(256), 0, stream,
                       x, Wx, bx, bh, XPh);
    hipLaunchKernelGGL(rnn_main, dim3(BATCH), dim3(TW), 0, stream,
                       XPh, Wy, by, Wpk, y);
}

// Round 20
// 978.164 us; speedup vs baseline: 1.2158x; 1.2158x over previous
//
#include <hip/hip_runtime.h>
#include <hip/hip_fp16.h>
#include <cstdint>
#include <cstddef>

// OwnVanillaRNN R20: R18 (MFMA persistent, 960 us, NREG=48 -- R19 proved 52
// spills) + DISTRIBUTED tanh. R18's hidden tail: tanh ran on 4/64 lanes per
// wave (~300-400 serial cyc/step). Now: MFMA phase -> real lanes store raw
// acc to f32 zbuf (4 conflict-free b128) -> barrier -> ALL 512 threads do
// ONE tanh each (z = zbuf[t] + xp[t]), write h[t] b16 contiguous -> barrier.
// XP fetched per-thread (1x2B coalesced/step; frees 16 xq/nxq regs).

constexpr int BATCH = 256;
constexpr int SEQ   = 512;
constexpr int IN    = 64;
constexpr int HID   = 512;
constexpr int OUT   = 64;
constexpr int TW    = 512;        // 8 waves
constexpr int FRW   = 64;         // frags/wave = 4 m-tiles x 16 k-tiles
constexpr int NREG  = 48;         // f = 0..47 named-SSA (m-tiles 0..2)
constexpr int NLDS  = 16;         // f = 48..63 in LDS (m-tile 3)

typedef _Float16 f16x8 __attribute__((ext_vector_type(8)));
typedef _Float16 half2v __attribute__((ext_vector_type(2)));
typedef float    f32x4 __attribute__((ext_vector_type(4)));

__device__ __forceinline__ uint32_t packh2(float lo, float hi) {
    return (uint32_t)__half_as_ushort(__float2half(lo)) |
           ((uint32_t)__half_as_ushort(__float2half(hi)) << 16);
}
__device__ __forceinline__ float fdot2(uint32_t w, uint32_t h, float acc) {
    return __builtin_amdgcn_fdot2(__builtin_bit_cast(half2v, w),
                                  __builtin_bit_cast(half2v, h), acc, false);
}

// Wpk[(w*64 + f)*64 + l]: wave w, frag f = i*16 + kt. A-layout (HW-verified):
// lane l holds Wh[64w + 16i + (l&15)][32kt + 8*(l>>4) + j], j = 0..7.
__global__ __launch_bounds__(256, 1)
void prep_w(const float* __restrict__ Wh, uint4* __restrict__ Wpk) {
    const int idx = blockIdx.x * 256 + threadIdx.x;   // 8*64*64 = 32768
    const int l  = idx & 63;
    const int wf = idx >> 6;
    const int w  = wf >> 6, f = wf & 63;
    const int i  = f >> 4, kt = f & 15;
    const int o  = 64 * w + 16 * i + (l & 15);
    const int d0 = 32 * kt + 8 * (l >> 4);
    const float* src = Wh + (size_t)o * HID + d0;
    uint4 d;
    d.x = packh2(src[0], src[1]);
    d.y = packh2(src[2], src[3]);
    d.z = packh2(src[4], src[5]);
    d.w = packh2(src[6], src[7]);
    Wpk[idx] = d;
}

// XP[b][t][c] = x[b][t][:] @ Wx[c][:] + bx[c] + bh[c], f16 (R13-proven).
__global__ __launch_bounds__(256, 1)
void prep_xp(const float* __restrict__ x, const float* __restrict__ Wx,
             const float* __restrict__ bx, const float* __restrict__ bh,
             __half* __restrict__ XPh) {
    __shared__ uint32_t xs2[16][32];
    const int tid = threadIdx.x;
    const size_t R0 = (size_t)blockIdx.x * 16;

    for (int e = tid; e < 16 * 32; e += 256) {
        const int r = e >> 5, j = e & 31;
        const float2 v = *(const float2*)(x + (R0 + r) * IN + 2 * j);
        xs2[r][j] = packh2(v.x, v.y);
    }
    const int c0 = 2 * tid, c1 = c0 + 1;
    uint32_t wa[32], wb[32];
    #pragma unroll
    for (int q = 0; q < 16; ++q) {
        const float4 va = *(const float4*)(Wx + (size_t)c0 * IN + 4 * q);
        wa[2 * q] = packh2(va.x, va.y); wa[2 * q + 1] = packh2(va.z, va.w);
        const float4 vb = *(const float4*)(Wx + (size_t)c1 * IN + 4 * q);
        wb[2 * q] = packh2(vb.x, vb.y); wb[2 * q + 1] = packh2(vb.z, vb.w);
    }
    const float b0 = bx[c0] + bh[c0], b1 = bx[c1] + bh[c1];
    __syncthreads();

    for (int r = 0; r < 16; ++r) {
        float a0 = b0, a1 = b1;
        #pragma unroll
        for (int j = 0; j < 32; ++j) {
            const uint32_t hx = xs2[r][j];
            a0 = fdot2(wa[j], hx, a0);
            a1 = fdot2(wb[j], hx, a1);
        }
        ((uint32_t*)XPh)[((R0 + r) * HID + c0) >> 1] = packh2(a0, a1);
    }
}

#define FR_LIST(M) \
  M(0)  M(1)  M(2)  M(3)  M(4)  M(5)  M(6)  M(7)  M(8)  M(9)  M(10) M(11) \
  M(12) M(13) M(14) M(15) M(16) M(17) M(18) M(19) M(20) M(21) M(22) M(23) \
  M(24) M(25) M(26) M(27) M(28) M(29) M(30) M(31) M(32) M(33) M(34) M(35) \
  M(36) M(37) M(38) M(39) M(40) M(41) M(42) M(43) M(44) M(45) M(46) M(47)

__global__ __launch_bounds__(TW, 2)
__attribute__((amdgpu_waves_per_eu(2, 2)))
void rnn_main(const __half* __restrict__ XPh, const float* __restrict__ Wy,
              const float* __restrict__ by, const uint4* __restrict__ Wpk,
              float* __restrict__ y) {
    __shared__ uint4 wl[NLDS * TW];                 // 128 KB: m-tile-3 frags
    __shared__ __align__(16) __half hb2[2][HID];    // double-buffered h
    __shared__ __align__(16) float  zbuf[HID];      // raw pre-activations
    __shared__ __align__(16) __half zsrc[8];        // 16B zeros (B cols 1-15)

    const int b = blockIdx.x, t = threadIdx.x;
    const int w = t >> 6, l = t & 63, g = l >> 4;
    const bool real = (l & 15) == 0;

    // ---- one-time: stage m-tile-3 frags to LDS (coalesced) ----
    #pragma unroll
    for (int j = 0; j < NLDS; ++j)
        wl[j * TW + t] = Wpk[((size_t)w * FRW + NREG + j) * 64 + l];

    // ---- one-time: 48 A-frags as named SSA (192 regs, arch+AGPR;
    // MFMA consumes AGPRs directly -> no reload tax) ----
    const uint4* wp = Wpk + (size_t)w * FRW * 64 + l;
#define DECL_W(f) const f16x8 w##f = __builtin_bit_cast(f16x8, wp[(f) * 64]);
    FR_LIST(DECL_W)
#undef DECL_W

    hb2[0][t] = __float2half(0.0f);   // h0 = 0 (t covers 512)
    if (t < 8) zsrc[t] = __float2half(0.0f);

    // Per-thread XP stream: thread t owns row t's xproj (bias pre-folded).
    const __half* XPt = XPh + (size_t)b * SEQ * HID + t;
    float xp = __half2float(XPt[0]);
    __syncthreads();

    const int bstep = real ? 4 : 0;

    #pragma unroll 1
    for (int tt = 0; tt < SEQ; ++tt) {
        const int c = tt & 1;

        const uint4* bq = real ? ((const uint4*)&hb2[c][0]) + g
                               : (const uint4*)zsrc;
        f32x4 acc0 = {0.f,0.f,0.f,0.f}, acc1 = {0.f,0.f,0.f,0.f};
        f32x4 acc2 = {0.f,0.f,0.f,0.f}, acc3 = {0.f,0.f,0.f,0.f};

#define KS(kt, fa, fb, fc) { \
        const f16x8 bfr = __builtin_bit_cast(f16x8, *bq); bq += bstep; \
        const f16x8 wv  = __builtin_bit_cast(f16x8, wl[(kt) * TW + t]); \
        acc0 = __builtin_amdgcn_mfma_f32_16x16x32_f16(fa, bfr, acc0, 0, 0, 0); \
        acc1 = __builtin_amdgcn_mfma_f32_16x16x32_f16(fb, bfr, acc1, 0, 0, 0); \
        acc2 = __builtin_amdgcn_mfma_f32_16x16x32_f16(fc, bfr, acc2, 0, 0, 0); \
        acc3 = __builtin_amdgcn_mfma_f32_16x16x32_f16(wv, bfr, acc3, 0, 0, 0); }
        KS(0,  w0,  w16, w32)  KS(1,  w1,  w17, w33)
        KS(2,  w2,  w18, w34)  KS(3,  w3,  w19, w35)
        KS(4,  w4,  w20, w36)  KS(5,  w5,  w21, w37)
        KS(6,  w6,  w22, w38)  KS(7,  w7,  w23, w39)
        KS(8,  w8,  w24, w40)  KS(9,  w9,  w25, w41)
        KS(10, w10, w26, w42)  KS(11, w11, w27, w43)
        KS(12, w12, w28, w44)  KS(13, w13, w29, w45)
        KS(14, w14, w30, w46)  KS(15, w15, w31, w47)
#undef KS

        // Raw z out: real lane 16g holds rows 64w+16i+4g..+3 (col 0).
        // Banks (16i+4g)%32 distinct across the 4 active lanes: conflict-free.
        if (real) {
            *(f32x4*)&zbuf[64 * w +  0 + 4 * g] = acc0;
            *(f32x4*)&zbuf[64 * w + 16 + 4 * g] = acc1;
            *(f32x4*)&zbuf[64 * w + 32 + 4 * g] = acc2;
            *(f32x4*)&zbuf[64 * w + 48 + 4 * g] = acc3;
        }
        __syncthreads();

        // Distributed tanh: every thread handles exactly its own row t.
        const float xpn = (tt + 1 < SEQ)
                        ? __half2float(XPt[(size_t)(tt + 1) * HID]) : 0.0f;
        const float z  = zbuf[t] + xp;
        const float hh = 1.f - 2.f * __builtin_amdgcn_rcpf(__expf(2.f * z) + 1.f);
        hb2[c ^ 1][t] = __float2half(hh);
        xp = xpn;
        __syncthreads();
    }

    // ---- epilogue: y = h_T @ Wy^T + by (final h in hb2[0]) ----
    if (t < OUT) {
        float acc = by[t];
        const float* wy = Wy + (size_t)t * HID;
        #pragma unroll 8
        for (int j = 0; j < HID; ++j)
            acc = fmaf(wy[j], __half2float(hb2[0][j]), acc);
        y[(size_t)b * OUT + t] = acc;
    }
}

extern "C" void kernel_launch(void* const* d_in, const int* in_sizes, int n_in,
                              void* d_out, int out_size, void* d_ws, size_t ws_size,
                              hipStream_t stream) {
    const float* x  = (const float*)d_in[0];
    const float* Wx = (const float*)d_in[1];
    const float* bx = (const float*)d_in[2];
    const float* Wh = (const float*)d_in[3];
    const float* bh = (const float*)d_in[4];
    const float* Wy = (const float*)d_in[5];
    const float* by = (const float*)d_in[6];
    float* y = (float*)d_out;

    uint4*  Wpk = (uint4*)d_ws;                          // 512 KB A-frags
    __half* XPh = (__half*)((char*)d_ws + (size_t)8 * FRW * 64 * 16);  // 128 MiB

    hipLaunchKernelGGL(prep_w, dim3(8 * FRW * 64 / 256), dim3(256), 0, stream,
                       Wh, Wpk);
    hipLaunchKernelGGL(prep_xp, dim3(BATCH * SEQ / 16), dim3(256), 0, stream,
                       x, Wx, bx, bh, XPh);
    hipLaunchKernelGGL(rnn_main, dim3(BATCH), dim3(TW), 0, stream,
                       XPh, Wy, by, Wpk, y);
}